// Round 5
// baseline (1616.797 us; speedup 1.0000x reference)
//
#include <hip/hip_runtime.h>
#include <hip/hip_bf16.h>
#include <stdint.h>

#define NN 100000
#define DD 256
#define EE 1600000
#define NB 391   // ceil(NN/256)

typedef short s16x8 __attribute__((ext_vector_type(8)));
typedef float f32x4 __attribute__((ext_vector_type(4)));

__device__ __forceinline__ unsigned short f2bf(float f) {
    union { float f; unsigned int u; } un; un.f = f;
    unsigned int u = un.u;
    unsigned int r = u + 0x7fffu + ((u >> 16) & 1u);  // RNE
    return (unsigned short)(r >> 16);
}
__device__ __forceinline__ float bf2f(unsigned short s) {
    union { unsigned int u; float f; } c; c.u = (unsigned int)s << 16; return c.f;
}

// ---- weight -> MFMA B-fragment order
__global__ void k_wconv(const float* __restrict__ W, unsigned short* __restrict__ Wf) {
    int t = blockIdx.x * 256 + threadIdx.x;   // 65536 total
    int j = t & 7;
    int l = (t >> 3) & 63;
    int c = (t >> 9) & 15;
    int s = t >> 13;
    int k   = s * 32 + (l >> 4) * 8 + j;
    int col = c * 16 + (l & 15);
    Wf[t] = f2bf(W[k * 256 + col]);
}

// ---- f32 -> bf16 bulk convert
__global__ void k_tobf16(const float4* __restrict__ in, ushort4* __restrict__ out, int n) {
    for (int i = blockIdx.x * 256 + threadIdx.x; i < n; i += gridDim.x * 256) {
        float4 v = in[i];
        ushort4 o;
        o.x = f2bf(v.x); o.y = f2bf(v.y); o.z = f2bf(v.z); o.w = f2bf(v.w);
        out[i] = o;
    }
}

// ================= CSR build =================
__global__ void k_deghist(const int* __restrict__ dst, int* __restrict__ deg) {
    int e = blockIdx.x * 256 + threadIdx.x;
    atomicAdd(&deg[dst[e]], 1);
}

__global__ void k_blocksum(const int* __restrict__ deg, int* __restrict__ bsum) {
    __shared__ int s[256];
    int t = blockIdx.x * 256 + threadIdx.x;
    s[threadIdx.x] = (t < NN) ? deg[t] : 0;
    __syncthreads();
    for (int off = 128; off > 0; off >>= 1) {
        if (threadIdx.x < off) s[threadIdx.x] += s[threadIdx.x + off];
        __syncthreads();
    }
    if (threadIdx.x == 0) bsum[blockIdx.x] = s[0];
}

__global__ void k_scanb(const int* __restrict__ bsum, int* __restrict__ boff,
                        int* __restrict__ rowptr) {
    __shared__ int s[512];
    int tid = threadIdx.x;
    s[tid] = (tid < NB) ? bsum[tid] : 0;
    __syncthreads();
    for (int off = 1; off < 512; off <<= 1) {
        int x = 0;
        if (tid >= off) x = s[tid - off];
        __syncthreads();
        if (tid >= off) s[tid] += x;
        __syncthreads();
    }
    if (tid < NB) boff[tid] = (tid > 0) ? s[tid - 1] : 0;
    if (tid == 0) rowptr[NN] = EE;
}

__global__ void k_finalscan(const int* __restrict__ deg, const int* __restrict__ boff,
                            int* __restrict__ rowptr) {
    __shared__ int s[256];
    int tid = threadIdx.x;
    int t = blockIdx.x * 256 + tid;
    int v = (t < NN) ? deg[t] : 0;
    s[tid] = v;
    __syncthreads();
    for (int off = 1; off < 256; off <<= 1) {
        int x = 0;
        if (tid >= off) x = s[tid - off];
        __syncthreads();
        if (tid >= off) s[tid] += x;
        __syncthreads();
    }
    if (t < NN) rowptr[t] = boff[blockIdx.x] + s[tid] - v;  // exclusive
}

__global__ void k_fill(const int* __restrict__ src, const int* __restrict__ dst,
                       const int* __restrict__ rowptr, int* __restrict__ cur,
                       int* __restrict__ eidx) {
    int e = blockIdx.x * 256 + threadIdx.x;
    int d = dst[e];
    int pos = atomicAdd(&cur[d], 1);
    eidx[rowptr[d] + pos] = src[e];
}

// ================= sliced gather =================
// XCD-affinity feature slicing: slice = blockIdx.x % 8 (32 cols = 16 ushort2 lanes).
// Wave processes 16 nodes serially; 4 edge-slots in parallel (16 lanes each),
// slot-reduced by shfl_xor(16/32). Input bf16; MODE 1 applies BN+ReLU per value.
template<int MODE>
__launch_bounds__(256)
__global__ void k_gather(const ushort2* __restrict__ h, const int* __restrict__ rowptr,
                         const int* __restrict__ eidx,
                         const float* __restrict__ s1, const float* __restrict__ s2,
                         const float* __restrict__ g, const float* __restrict__ be,
                         ushort2* __restrict__ agg) {
    const int slice = blockIdx.x & 7;
    const int chunk = blockIdx.x >> 3;
    const int tid  = threadIdx.x;
    const int wave = tid >> 6;
    const int lane = tid & 63;
    const int slot = lane >> 4;
    const int l16  = lane & 15;

    const ushort2* hp = h + slice * 16 + l16;      // + node*128
    ushort2* ap = agg + slice * 16 + l16;

    float kk0 = 1.f, kk1 = 1.f, sh0 = 0.f, sh1 = 0.f;
    if constexpr (MODE == 1) {
        int c0 = slice * 32 + l16 * 2;
        float2 s1v = *(const float2*)(s1 + c0);
        float2 s2v = *(const float2*)(s2 + c0);
        float2 gv  = *(const float2*)(g + c0);
        float2 bev = *(const float2*)(be + c0);
        float m, var;
        m = s1v.x * (1.f/NN); var = s2v.x * (1.f/NN) - m*m;
        kk0 = rsqrtf(var + 1e-5f) * gv.x; sh0 = bev.x - m * kk0;
        m = s1v.y * (1.f/NN); var = s2v.y * (1.f/NN) - m*m;
        kk1 = rsqrtf(var + 1e-5f) * gv.y; sh1 = bev.y - m * kk1;
    }

    const int nbase = chunk * 64 + wave * 16;
    for (int j = 0; j < 16; j++) {
        int node = nbase + j;
        if (node >= NN) return;
        int beg = rowptr[node];
        int end = rowptr[node + 1];

        float a0 = 0.f, a1 = 0.f, b0 = 0.f, b1 = 0.f;
        int i = beg + slot;
        for (; i + 4 < end; i += 8) {
            int sA = eidx[i];
            int sB = eidx[i + 4];
            ushort2 uA = hp[(size_t)sA * 128];
            ushort2 uB = hp[(size_t)sB * 128];
            if constexpr (MODE == 1) {
                a0 += fmaxf(bf2f(uA.x) * kk0 + sh0, 0.f);
                a1 += fmaxf(bf2f(uA.y) * kk1 + sh1, 0.f);
                b0 += fmaxf(bf2f(uB.x) * kk0 + sh0, 0.f);
                b1 += fmaxf(bf2f(uB.y) * kk1 + sh1, 0.f);
            } else {
                a0 += bf2f(uA.x); a1 += bf2f(uA.y);
                b0 += bf2f(uB.x); b1 += bf2f(uB.y);
            }
        }
        if (i < end) {
            int sA = eidx[i];
            ushort2 uA = hp[(size_t)sA * 128];
            if constexpr (MODE == 1) {
                a0 += fmaxf(bf2f(uA.x) * kk0 + sh0, 0.f);
                a1 += fmaxf(bf2f(uA.y) * kk1 + sh1, 0.f);
            } else {
                a0 += bf2f(uA.x); a1 += bf2f(uA.y);
            }
        }
        a0 += b0; a1 += b1;
        // reduce across 4 slots (lanes differing in bits 4,5)
        a0 += __shfl_xor(a0, 16); a0 += __shfl_xor(a0, 32);
        a1 += __shfl_xor(a1, 16); a1 += __shfl_xor(a1, 32);

        if (slot == 0) {
            ushort2 u = hp[(size_t)node * 128];
            if constexpr (MODE == 1) {
                a0 += fmaxf(bf2f(u.x) * kk0 + sh0, 0.f);
                a1 += fmaxf(bf2f(u.y) * kk1 + sh1, 0.f);
            } else {
                a0 += bf2f(u.x); a1 += bf2f(u.y);
            }
            ushort2 o;
            o.x = f2bf(a0); o.y = f2bf(a1);
            ap[(size_t)node * 128] = o;
        }
    }
}

// ================= GEMM =================
// A: bf16 (ABF16) or f32 (opt. fused BN+ReLU in staging). C: f32 or bf16.
// STATS: fused per-column sum / sum-sq of C into s1o/s2o (pre-zeroed, atomics).
template<bool ABF16, bool BNSTAGE, bool OUTBF16, bool STATS>
__launch_bounds__(256)
__global__ void k_gemm(const void* __restrict__ Av, const unsigned short* __restrict__ Wf,
                       const float* __restrict__ bias,
                       const float* __restrict__ s1, const float* __restrict__ s2,
                       const float* __restrict__ g, const float* __restrict__ be,
                       void* __restrict__ Cv,
                       float* __restrict__ s1o, float* __restrict__ s2o, int M) {
    __shared__ s16x8 Al[2048];   // 64 rows x 256 cols bf16 = 32 KB, XOR-swizzled
    __shared__ float sbn[512];
    const int tid = threadIdx.x;
    const int base_row = blockIdx.x * 64;

    if constexpr (STATS) {
        sbn[tid] = 0.f; sbn[tid + 256] = 0.f;
    }

    #pragma unroll
    for (int i = 0; i < 8; i++) {
        int chunk = tid + i * 256;
        int row = chunk >> 5;
        int k0  = (chunk & 31) * 8;
        int gr = base_row + row;
        s16x8 sv;
        if constexpr (ABF16) {
            if (gr < M)
                sv = *(const s16x8*)((const unsigned short*)Av + (size_t)gr * 256 + k0);
            else
                sv = (s16x8){0,0,0,0,0,0,0,0};
        } else {
            float vv[8];
            if (gr < M) {
                const float4* gp = (const float4*)((const float*)Av + (size_t)gr * 256 + k0);
                float4 v0 = gp[0], v1 = gp[1];
                vv[0]=v0.x; vv[1]=v0.y; vv[2]=v0.z; vv[3]=v0.w;
                vv[4]=v1.x; vv[5]=v1.y; vv[6]=v1.z; vv[7]=v1.w;
            } else {
                #pragma unroll
                for (int j = 0; j < 8; j++) vv[j] = 0.f;
            }
            if constexpr (BNSTAGE) {
                #pragma unroll
                for (int j = 0; j < 8; j++) {
                    float m  = s1[k0+j] * (1.f/NN);
                    float var = s2[k0+j] * (1.f/NN) - m*m;
                    float kk = rsqrtf(var + 1e-5f) * g[k0+j];
                    float shv = be[k0+j] - m * kk;
                    vv[j] = fmaxf(vv[j] * kk + shv, 0.f);
                }
            }
            #pragma unroll
            for (int j = 0; j < 8; j++) sv[j] = (short)f2bf(vv[j]);
        }
        int byte = (row * 512 + k0 * 2) ^ ((row & 7) << 4);
        Al[byte >> 4] = sv;
    }
    __syncthreads();

    const int lane = tid & 63;
    const int w = tid >> 6;
    const int wr = w >> 1;
    const int wc = w & 1;

    f32x4 acc[2][8];
    #pragma unroll
    for (int m = 0; m < 2; m++)
        #pragma unroll
        for (int c = 0; c < 8; c++)
            acc[m][c] = (f32x4){0.f, 0.f, 0.f, 0.f};

    #pragma unroll
    for (int s = 0; s < 8; s++) {
        s16x8 a[2], b[8];
        #pragma unroll
        for (int m = 0; m < 2; m++) {
            int row = wr * 32 + m * 16 + (lane & 15);
            int koff = s * 32 + (lane >> 4) * 8;
            int byte = (row * 512 + koff * 2) ^ ((row & 7) << 4);
            a[m] = Al[byte >> 4];
        }
        const unsigned short* wp = Wf + (size_t)((s * 16 + wc * 8) * 64 + lane) * 8;
        #pragma unroll
        for (int c = 0; c < 8; c++)
            b[c] = *(const s16x8*)(wp + (size_t)c * 512);
        #pragma unroll
        for (int m = 0; m < 2; m++)
            #pragma unroll
            for (int c = 0; c < 8; c++)
                acc[m][c] = __builtin_amdgcn_mfma_f32_16x16x32_bf16(a[m], b[c], acc[m][c], 0, 0, 0);
    }

    #pragma unroll
    for (int m = 0; m < 2; m++) {
        int row0 = base_row + wr * 32 + m * 16 + (lane >> 4) * 4;
        #pragma unroll
        for (int c = 0; c < 8; c++) {
            int col = wc * 128 + c * 16 + (lane & 15);
            float bv = bias[col];
            float p1 = 0.f, p2 = 0.f;
            #pragma unroll
            for (int r = 0; r < 4; r++) {
                int row = row0 + r;
                if (row < M) {
                    float v = acc[m][c][r] + bv;
                    if constexpr (OUTBF16)
                        ((unsigned short*)Cv)[(size_t)row * 256 + col] = f2bf(v);
                    else
                        ((float*)Cv)[(size_t)row * 256 + col] = v;
                    if constexpr (STATS) { p1 += v; p2 += v * v; }
                }
            }
            if constexpr (STATS) {
                p1 += __shfl_xor(p1, 16); p1 += __shfl_xor(p1, 32);
                p2 += __shfl_xor(p2, 16); p2 += __shfl_xor(p2, 32);
                if (lane < 16) {
                    atomicAdd(&sbn[col], p1);
                    atomicAdd(&sbn[col + 256], p2);
                }
            }
        }
    }
    if constexpr (STATS) {
        __syncthreads();
        atomicAdd(&s1o[tid & 255], sbn[tid]);
        atomicAdd(&s2o[tid & 255], sbn[tid + 256]);
    }
}

extern "C" void kernel_launch(void* const* d_in, const int* in_sizes, int n_in,
                              void* d_out, int out_size, void* d_ws, size_t ws_size,
                              hipStream_t stream) {
    const float* x   = (const float*)d_in[0];
    const int*   src = (const int*)d_in[1];
    const int*   dst = (const int*)d_in[2];
    const float* W[6]    = { (const float*)d_in[3],  (const float*)d_in[7],
                             (const float*)d_in[11], (const float*)d_in[15],
                             (const float*)d_in[19], (const float*)d_in[23] };
    const float* Bias[6] = { (const float*)d_in[4],  (const float*)d_in[8],
                             (const float*)d_in[12], (const float*)d_in[16],
                             (const float*)d_in[20], (const float*)d_in[24] };
    const float* Gam[5]  = { (const float*)d_in[5],  (const float*)d_in[9],
                             (const float*)d_in[13], (const float*)d_in[17],
                             (const float*)d_in[21] };
    const float* Bet[5]  = { (const float*)d_in[6],  (const float*)d_in[10],
                             (const float*)d_in[14], (const float*)d_in[18],
                             (const float*)d_in[22] };

    char* ws = (char*)d_ws;
    unsigned short* Wf = (unsigned short*)ws;              // 786,432 B
    float* stats = (float*)(ws + 786432);                  // 10,240 B
    unsigned short* aggbf = (unsigned short*)(ws + (1 << 20));       // 51.2 MB
    unsigned short* z2bf  = aggbf + (size_t)NN * DD;                 // 51.2 MB
    char* csr = ws + (1 << 20) + 102400000;
    int* rowptr = (int*)csr;
    int* deg    = (int*)(csr + 400128);
    int* cur    = (int*)(csr + 800128);
    int* bsum   = (int*)(csr + 1200128);
    int* boff   = (int*)(csr + 1202176);
    int* eidx   = (int*)(csr + 1204224);
    float* OUT = (float*)d_out;

    // ---- prep
    for (int i = 0; i < 6; i++)
        k_wconv<<<256, 256, 0, stream>>>(W[i], Wf + (size_t)i * 65536);
    hipMemsetAsync(stats, 0, 5 * 512 * sizeof(float), stream);
    hipMemsetAsync(deg, 0, NN * sizeof(int), stream);
    hipMemsetAsync(cur, 0, NN * sizeof(int), stream);

    k_deghist<<<EE / 256, 256, 0, stream>>>(dst, deg);
    k_blocksum<<<NB, 256, 0, stream>>>(deg, bsum);
    k_scanb<<<1, 512, 0, stream>>>(bsum, boff, rowptr);
    k_finalscan<<<NB, 256, 0, stream>>>(deg, boff, rowptr);
    k_fill<<<EE / 256, 256, 0, stream>>>(src, dst, rowptr, cur, eidx);

    // x -> bf16 (into z2bf; dead until first gemm2bf)
    k_tobf16<<<8192, 256, 0, stream>>>((const float4*)x, (ushort4*)z2bf, NN * DD / 4);

    const int GCH = (NN + 63) / 64;          // 64 nodes per chunk
    const int GG  = GCH * 8;                 // x8 slices
    float* st[5];
    for (int i = 0; i < 5; i++) st[i] = stats + i * 512;

    // bf16 A -> f32 C, fused stats
    auto gemm1 = [&](const unsigned short* A, int wi, int si, float* C) {
        k_gemm<true, false, false, true><<<1563, 256, 0, stream>>>(
            A, Wf + (size_t)wi * 65536, Bias[wi], nullptr, nullptr, nullptr, nullptr,
            C, st[si], st[si] + 256, NN);
    };
    // f32 A + BN staged -> bf16 C, fused stats
    auto gemm2bf = [&](const float* A, int wi, int si, int so, unsigned short* C) {
        k_gemm<false, true, true, true><<<1563, 256, 0, stream>>>(
            A, Wf + (size_t)wi * 65536, Bias[wi], st[si], st[si] + 256, Gam[si], Bet[si],
            C, st[so], st[so] + 256, NN);
    };

    // ---- Layer 0  (h = x as bf16, no BN)
    k_gather<0><<<GG, 256, 0, stream>>>((const ushort2*)z2bf, rowptr, eidx,
                                        nullptr, nullptr, nullptr, nullptr,
                                        (ushort2*)aggbf);
    gemm1(aggbf, 0, 0, OUT);
    gemm2bf(OUT, 1, 0, 1, z2bf);

    // ---- Layer 1
    k_gather<1><<<GG, 256, 0, stream>>>((const ushort2*)z2bf, rowptr, eidx,
                                        st[1], st[1] + 256, Gam[1], Bet[1],
                                        (ushort2*)aggbf);
    gemm1(aggbf, 2, 2, OUT);
    gemm2bf(OUT, 3, 2, 3, z2bf);

    // ---- Layer 2
    k_gather<1><<<GG, 256, 0, stream>>>((const ushort2*)z2bf, rowptr, eidx,
                                        st[3], st[3] + 256, Gam[3], Bet[3],
                                        (ushort2*)aggbf);
    gemm1(aggbf, 4, 4, OUT);
    // final: f32 z1 in OUT -> BN+ReLU staged -> GEMM -> f32 OUT (in-place safe), no stats
    k_gemm<false, true, false, false><<<1563, 256, 0, stream>>>(
        OUT, Wf + (size_t)5 * 65536, Bias[5], st[4], st[4] + 256, Gam[4], Bet[4],
        OUT, nullptr, nullptr, NN);
}

// Round 6
// 1126.451 us; speedup vs baseline: 1.4353x; 1.4353x over previous
//
#include <hip/hip_runtime.h>
#include <hip/hip_bf16.h>
#include <stdint.h>

#define NN 100000
#define DD 256
#define EE 1600000
#define NB 391   // ceil(NN/256)

typedef short s16x8 __attribute__((ext_vector_type(8)));
typedef float f32x4 __attribute__((ext_vector_type(4)));

__device__ __forceinline__ unsigned short f2bf(float f) {
    union { float f; unsigned int u; } un; un.f = f;
    unsigned int u = un.u;
    unsigned int r = u + 0x7fffu + ((u >> 16) & 1u);  // RNE
    return (unsigned short)(r >> 16);
}
__device__ __forceinline__ float bf2f(unsigned short s) {
    union { unsigned int u; float f; } c; c.u = (unsigned int)s << 16; return c.f;
}

// ---- weight -> MFMA B-fragment order
__global__ void k_wconv(const float* __restrict__ W, unsigned short* __restrict__ Wf) {
    int t = blockIdx.x * 256 + threadIdx.x;   // 65536 total
    int j = t & 7;
    int l = (t >> 3) & 63;
    int c = (t >> 9) & 15;
    int s = t >> 13;
    int k   = s * 32 + (l >> 4) * 8 + j;
    int col = c * 16 + (l & 15);
    Wf[t] = f2bf(W[k * 256 + col]);
}

// ================= CSR build =================
__global__ void k_deghist(const int* __restrict__ dst, int* __restrict__ deg) {
    int e = blockIdx.x * 256 + threadIdx.x;
    atomicAdd(&deg[dst[e]], 1);
}

__global__ void k_blocksum(const int* __restrict__ deg, int* __restrict__ bsum) {
    __shared__ int s[256];
    int t = blockIdx.x * 256 + threadIdx.x;
    s[threadIdx.x] = (t < NN) ? deg[t] : 0;
    __syncthreads();
    for (int off = 128; off > 0; off >>= 1) {
        if (threadIdx.x < off) s[threadIdx.x] += s[threadIdx.x + off];
        __syncthreads();
    }
    if (threadIdx.x == 0) bsum[blockIdx.x] = s[0];
}

__global__ void k_scanb(const int* __restrict__ bsum, int* __restrict__ boff,
                        int* __restrict__ rowptr) {
    __shared__ int s[512];
    int tid = threadIdx.x;
    s[tid] = (tid < NB) ? bsum[tid] : 0;
    __syncthreads();
    for (int off = 1; off < 512; off <<= 1) {
        int x = 0;
        if (tid >= off) x = s[tid - off];
        __syncthreads();
        if (tid >= off) s[tid] += x;
        __syncthreads();
    }
    if (tid < NB) boff[tid] = (tid > 0) ? s[tid - 1] : 0;
    if (tid == 0) rowptr[NN] = EE;
}

__global__ void k_finalscan(const int* __restrict__ deg, const int* __restrict__ boff,
                            int* __restrict__ rowptr) {
    __shared__ int s[256];
    int tid = threadIdx.x;
    int t = blockIdx.x * 256 + tid;
    int v = (t < NN) ? deg[t] : 0;
    s[tid] = v;
    __syncthreads();
    for (int off = 1; off < 256; off <<= 1) {
        int x = 0;
        if (tid >= off) x = s[tid - off];
        __syncthreads();
        if (tid >= off) s[tid] += x;
        __syncthreads();
    }
    if (t < NN) rowptr[t] = boff[blockIdx.x] + s[tid] - v;  // exclusive
}

__global__ void k_fill(const int* __restrict__ src, const int* __restrict__ dst,
                       const int* __restrict__ rowptr, int* __restrict__ cur,
                       int* __restrict__ eidx) {
    int e = blockIdx.x * 256 + threadIdx.x;
    int d = dst[e];
    int pos = atomicAdd(&cur[d], 1);
    eidx[rowptr[d] + pos] = src[e];
}

// ================= gather (R4 form: one wave per node, 8-deep) =================
// MODE 0: f32 input, no BN (layer 0).  MODE 1: bf16 raw-z input, fused BN+ReLU.
template<int MODE>
__launch_bounds__(256)
__global__ void k_gather(const void* __restrict__ hv, const int* __restrict__ rowptr,
                         const int* __restrict__ eidx,
                         const float* __restrict__ s1, const float* __restrict__ s2,
                         const float* __restrict__ g, const float* __restrict__ be,
                         ushort4* __restrict__ agg) {
    int gid = blockIdx.x * 256 + threadIdx.x;
    int node = gid >> 6;
    int lane = gid & 63;
    if (node >= NN) return;
    int beg = rowptr[node];
    int end = rowptr[node + 1];
    float4 acc;

    if constexpr (MODE == 0) {
        const float4* h = (const float4*)hv;
        acc = h[(size_t)node * 64 + lane];
        int i = beg;
        for (; i + 8 <= end; i += 8) {
            int idx[8];
            #pragma unroll
            for (int j = 0; j < 8; j++) idx[j] = eidx[i + j];
            float4 v[8];
            #pragma unroll
            for (int j = 0; j < 8; j++) v[j] = h[(size_t)idx[j] * 64 + lane];
            #pragma unroll
            for (int j = 0; j < 8; j++) {
                acc.x += v[j].x; acc.y += v[j].y; acc.z += v[j].z; acc.w += v[j].w;
            }
        }
        for (; i + 4 <= end; i += 4) {
            int idx[4];
            #pragma unroll
            for (int j = 0; j < 4; j++) idx[j] = eidx[i + j];
            float4 v[4];
            #pragma unroll
            for (int j = 0; j < 4; j++) v[j] = h[(size_t)idx[j] * 64 + lane];
            #pragma unroll
            for (int j = 0; j < 4; j++) {
                acc.x += v[j].x; acc.y += v[j].y; acc.z += v[j].z; acc.w += v[j].w;
            }
        }
        for (; i + 2 <= end; i += 2) {
            float4 v0 = h[(size_t)eidx[i] * 64 + lane];
            float4 v1 = h[(size_t)eidx[i + 1] * 64 + lane];
            acc.x += v0.x + v1.x; acc.y += v0.y + v1.y;
            acc.z += v0.z + v1.z; acc.w += v0.w + v1.w;
        }
        if (i < end) {
            float4 v = h[(size_t)eidx[i] * 64 + lane];
            acc.x += v.x; acc.y += v.y; acc.z += v.z; acc.w += v.w;
        }
    } else {
        const ushort4* h = (const ushort4*)hv;
        int c0 = lane * 4;
        float4 s1v = *(const float4*)(s1 + c0);
        float4 s2v = *(const float4*)(s2 + c0);
        float4 gv  = *(const float4*)(g + c0);
        float4 bev = *(const float4*)(be + c0);
        float kk[4], sh[4];
        {
            float m, var;
            m = s1v.x * (1.f/NN); var = s2v.x * (1.f/NN) - m*m; kk[0] = rsqrtf(var+1e-5f)*gv.x; sh[0] = bev.x - m*kk[0];
            m = s1v.y * (1.f/NN); var = s2v.y * (1.f/NN) - m*m; kk[1] = rsqrtf(var+1e-5f)*gv.y; sh[1] = bev.y - m*kk[1];
            m = s1v.z * (1.f/NN); var = s2v.z * (1.f/NN) - m*m; kk[2] = rsqrtf(var+1e-5f)*gv.z; sh[2] = bev.z - m*kk[2];
            m = s1v.w * (1.f/NN); var = s2v.w * (1.f/NN) - m*m; kk[3] = rsqrtf(var+1e-5f)*gv.w; sh[3] = bev.w - m*kk[3];
        }
        ushort4 u = h[(size_t)node * 64 + lane];
        acc.x = fmaxf(bf2f(u.x) * kk[0] + sh[0], 0.f);
        acc.y = fmaxf(bf2f(u.y) * kk[1] + sh[1], 0.f);
        acc.z = fmaxf(bf2f(u.z) * kk[2] + sh[2], 0.f);
        acc.w = fmaxf(bf2f(u.w) * kk[3] + sh[3], 0.f);
        int i = beg;
        for (; i + 8 <= end; i += 8) {
            int idx[8];
            #pragma unroll
            for (int j = 0; j < 8; j++) idx[j] = eidx[i + j];
            ushort4 v[8];
            #pragma unroll
            for (int j = 0; j < 8; j++) v[j] = h[(size_t)idx[j] * 64 + lane];
            #pragma unroll
            for (int j = 0; j < 8; j++) {
                acc.x += fmaxf(bf2f(v[j].x) * kk[0] + sh[0], 0.f);
                acc.y += fmaxf(bf2f(v[j].y) * kk[1] + sh[1], 0.f);
                acc.z += fmaxf(bf2f(v[j].z) * kk[2] + sh[2], 0.f);
                acc.w += fmaxf(bf2f(v[j].w) * kk[3] + sh[3], 0.f);
            }
        }
        for (; i + 4 <= end; i += 4) {
            int idx[4];
            #pragma unroll
            for (int j = 0; j < 4; j++) idx[j] = eidx[i + j];
            ushort4 v[4];
            #pragma unroll
            for (int j = 0; j < 4; j++) v[j] = h[(size_t)idx[j] * 64 + lane];
            #pragma unroll
            for (int j = 0; j < 4; j++) {
                acc.x += fmaxf(bf2f(v[j].x) * kk[0] + sh[0], 0.f);
                acc.y += fmaxf(bf2f(v[j].y) * kk[1] + sh[1], 0.f);
                acc.z += fmaxf(bf2f(v[j].z) * kk[2] + sh[2], 0.f);
                acc.w += fmaxf(bf2f(v[j].w) * kk[3] + sh[3], 0.f);
            }
        }
        for (; i < end; i++) {
            ushort4 a = h[(size_t)eidx[i] * 64 + lane];
            acc.x += fmaxf(bf2f(a.x) * kk[0] + sh[0], 0.f);
            acc.y += fmaxf(bf2f(a.y) * kk[1] + sh[1], 0.f);
            acc.z += fmaxf(bf2f(a.z) * kk[2] + sh[2], 0.f);
            acc.w += fmaxf(bf2f(a.w) * kk[3] + sh[3], 0.f);
        }
    }
    ushort4 o;
    o.x = f2bf(acc.x); o.y = f2bf(acc.y); o.z = f2bf(acc.z); o.w = f2bf(acc.w);
    agg[(size_t)node * 64 + lane] = o;
}

// ================= GEMM =================
// A: bf16 (ABF16) or f32; BNSTAGE applies BN+ReLU during staging (works for both).
// C: f32 or bf16. STATS: fused per-column sum/sum-sq of f32 pre-round C values.
template<bool ABF16, bool BNSTAGE, bool OUTBF16, bool STATS>
__launch_bounds__(256)
__global__ void k_gemm(const void* __restrict__ Av, const unsigned short* __restrict__ Wf,
                       const float* __restrict__ bias,
                       const float* __restrict__ s1, const float* __restrict__ s2,
                       const float* __restrict__ g, const float* __restrict__ be,
                       void* __restrict__ Cv,
                       float* __restrict__ s1o, float* __restrict__ s2o, int M) {
    __shared__ s16x8 Al[2048];   // 64 rows x 256 cols bf16 = 32 KB, XOR-swizzled
    __shared__ float sbn[512];
    const int tid = threadIdx.x;
    const int base_row = blockIdx.x * 64;

    if constexpr (STATS) {
        sbn[tid] = 0.f; sbn[tid + 256] = 0.f;
    }

    #pragma unroll
    for (int i = 0; i < 8; i++) {
        int chunk = tid + i * 256;
        int row = chunk >> 5;
        int k0  = (chunk & 31) * 8;
        int gr = base_row + row;
        s16x8 sv;
        if constexpr (ABF16) {
            if (gr < M)
                sv = *(const s16x8*)((const unsigned short*)Av + (size_t)gr * 256 + k0);
            else
                sv = (s16x8){0,0,0,0,0,0,0,0};
            if constexpr (BNSTAGE) {
                #pragma unroll
                for (int j = 0; j < 8; j++) {
                    float m  = s1[k0+j] * (1.f/NN);
                    float var = s2[k0+j] * (1.f/NN) - m*m;
                    float kk = rsqrtf(var + 1e-5f) * g[k0+j];
                    float shv = be[k0+j] - m * kk;
                    float f = fmaxf(bf2f((unsigned short)sv[j]) * kk + shv, 0.f);
                    sv[j] = (short)f2bf(f);
                }
            }
        } else {
            float vv[8];
            if (gr < M) {
                const float4* gp = (const float4*)((const float*)Av + (size_t)gr * 256 + k0);
                float4 v0 = gp[0], v1 = gp[1];
                vv[0]=v0.x; vv[1]=v0.y; vv[2]=v0.z; vv[3]=v0.w;
                vv[4]=v1.x; vv[5]=v1.y; vv[6]=v1.z; vv[7]=v1.w;
            } else {
                #pragma unroll
                for (int j = 0; j < 8; j++) vv[j] = 0.f;
            }
            if constexpr (BNSTAGE) {
                #pragma unroll
                for (int j = 0; j < 8; j++) {
                    float m  = s1[k0+j] * (1.f/NN);
                    float var = s2[k0+j] * (1.f/NN) - m*m;
                    float kk = rsqrtf(var + 1e-5f) * g[k0+j];
                    float shv = be[k0+j] - m * kk;
                    vv[j] = fmaxf(vv[j] * kk + shv, 0.f);
                }
            }
            #pragma unroll
            for (int j = 0; j < 8; j++) sv[j] = (short)f2bf(vv[j]);
        }
        int byte = (row * 512 + k0 * 2) ^ ((row & 7) << 4);
        Al[byte >> 4] = sv;
    }
    __syncthreads();

    const int lane = tid & 63;
    const int w = tid >> 6;
    const int wr = w >> 1;
    const int wc = w & 1;

    f32x4 acc[2][8];
    #pragma unroll
    for (int m = 0; m < 2; m++)
        #pragma unroll
        for (int c = 0; c < 8; c++)
            acc[m][c] = (f32x4){0.f, 0.f, 0.f, 0.f};

    #pragma unroll
    for (int s = 0; s < 8; s++) {
        s16x8 a[2], b[8];
        #pragma unroll
        for (int m = 0; m < 2; m++) {
            int row = wr * 32 + m * 16 + (lane & 15);
            int koff = s * 32 + (lane >> 4) * 8;
            int byte = (row * 512 + koff * 2) ^ ((row & 7) << 4);
            a[m] = Al[byte >> 4];
        }
        const unsigned short* wp = Wf + (size_t)((s * 16 + wc * 8) * 64 + lane) * 8;
        #pragma unroll
        for (int c = 0; c < 8; c++)
            b[c] = *(const s16x8*)(wp + (size_t)c * 512);
        #pragma unroll
        for (int m = 0; m < 2; m++)
            #pragma unroll
            for (int c = 0; c < 8; c++)
                acc[m][c] = __builtin_amdgcn_mfma_f32_16x16x32_bf16(a[m], b[c], acc[m][c], 0, 0, 0);
    }

    #pragma unroll
    for (int m = 0; m < 2; m++) {
        int row0 = base_row + wr * 32 + m * 16 + (lane >> 4) * 4;
        #pragma unroll
        for (int c = 0; c < 8; c++) {
            int col = wc * 128 + c * 16 + (lane & 15);
            float bv = bias[col];
            float p1 = 0.f, p2 = 0.f;
            #pragma unroll
            for (int r = 0; r < 4; r++) {
                int row = row0 + r;
                if (row < M) {
                    float v = acc[m][c][r] + bv;
                    if constexpr (OUTBF16)
                        ((unsigned short*)Cv)[(size_t)row * 256 + col] = f2bf(v);
                    else
                        ((float*)Cv)[(size_t)row * 256 + col] = v;
                    if constexpr (STATS) { p1 += v; p2 += v * v; }
                }
            }
            if constexpr (STATS) {
                p1 += __shfl_xor(p1, 16); p1 += __shfl_xor(p1, 32);
                p2 += __shfl_xor(p2, 16); p2 += __shfl_xor(p2, 32);
                if (lane < 16) {
                    atomicAdd(&sbn[col], p1);
                    atomicAdd(&sbn[col + 256], p2);
                }
            }
        }
    }
    if constexpr (STATS) {
        __syncthreads();
        atomicAdd(&s1o[tid & 255], sbn[tid]);
        atomicAdd(&s2o[tid & 255], sbn[tid + 256]);
    }
}

extern "C" void kernel_launch(void* const* d_in, const int* in_sizes, int n_in,
                              void* d_out, int out_size, void* d_ws, size_t ws_size,
                              hipStream_t stream) {
    const float* x   = (const float*)d_in[0];
    const int*   src = (const int*)d_in[1];
    const int*   dst = (const int*)d_in[2];
    const float* W[6]    = { (const float*)d_in[3],  (const float*)d_in[7],
                             (const float*)d_in[11], (const float*)d_in[15],
                             (const float*)d_in[19], (const float*)d_in[23] };
    const float* Bias[6] = { (const float*)d_in[4],  (const float*)d_in[8],
                             (const float*)d_in[12], (const float*)d_in[16],
                             (const float*)d_in[20], (const float*)d_in[24] };
    const float* Gam[5]  = { (const float*)d_in[5],  (const float*)d_in[9],
                             (const float*)d_in[13], (const float*)d_in[17],
                             (const float*)d_in[21] };
    const float* Bet[5]  = { (const float*)d_in[6],  (const float*)d_in[10],
                             (const float*)d_in[14], (const float*)d_in[18],
                             (const float*)d_in[22] };

    char* ws = (char*)d_ws;
    unsigned short* Wf = (unsigned short*)ws;              // 786,432 B
    float* stats = (float*)(ws + 786432);                  // 10,240 B
    unsigned short* aggbf = (unsigned short*)(ws + (1 << 20));       // 51.2 MB (agg, then z1)
    unsigned short* z2bf  = aggbf + (size_t)NN * DD;                 // 51.2 MB
    char* csr = ws + (1 << 20) + 102400000;
    int* rowptr = (int*)csr;
    int* deg    = (int*)(csr + 400128);
    int* cur    = (int*)(csr + 800128);
    int* bsum   = (int*)(csr + 1200128);
    int* boff   = (int*)(csr + 1202176);
    int* eidx   = (int*)(csr + 1204224);
    float* OUT = (float*)d_out;

    // ---- prep
    for (int i = 0; i < 6; i++)
        k_wconv<<<256, 256, 0, stream>>>(W[i], Wf + (size_t)i * 65536);
    hipMemsetAsync(stats, 0, 5 * 512 * sizeof(float), stream);
    hipMemsetAsync(deg, 0, NN * sizeof(int), stream);
    hipMemsetAsync(cur, 0, NN * sizeof(int), stream);

    k_deghist<<<EE / 256, 256, 0, stream>>>(dst, deg);
    k_blocksum<<<NB, 256, 0, stream>>>(deg, bsum);
    k_scanb<<<1, 512, 0, stream>>>(bsum, boff, rowptr);
    k_finalscan<<<NB, 256, 0, stream>>>(deg, boff, rowptr);
    k_fill<<<EE / 256, 256, 0, stream>>>(src, dst, rowptr, cur, eidx);

    const int GG = (NN * 64 + 255) / 256;
    float* st[5];
    for (int i = 0; i < 5; i++) st[i] = stats + i * 512;

    // GEMM1: bf16 A -> bf16 C IN-PLACE (A==C, block-local rows), fused stats
    auto gemm1 = [&](unsigned short* A, int wi, int si) {
        k_gemm<true, false, true, true><<<1563, 256, 0, stream>>>(
            A, Wf + (size_t)wi * 65536, Bias[wi], nullptr, nullptr, nullptr, nullptr,
            A, st[si], st[si] + 256, NN);
    };
    // GEMM2: bf16 A + BN staged -> bf16 C, fused stats
    auto gemm2 = [&](const unsigned short* A, int wi, int si, int so, unsigned short* C) {
        k_gemm<true, true, true, true><<<1563, 256, 0, stream>>>(
            A, Wf + (size_t)wi * 65536, Bias[wi], st[si], st[si] + 256, Gam[si], Bet[si],
            C, st[so], st[so] + 256, NN);
    };

    // ---- Layer 0 (h = x, f32 gather)
    k_gather<0><<<GG, 256, 0, stream>>>(x, rowptr, eidx, nullptr, nullptr, nullptr, nullptr,
                                        (ushort4*)aggbf);
    gemm1(aggbf, 0, 0);                     // z1 bf16 in aggbf
    gemm2(aggbf, 1, 0, 1, z2bf);            // z2 bf16 in z2bf

    // ---- Layer 1
    k_gather<1><<<GG, 256, 0, stream>>>(z2bf, rowptr, eidx, st[1], st[1] + 256, Gam[1], Bet[1],
                                        (ushort4*)aggbf);
    gemm1(aggbf, 2, 2);
    gemm2(aggbf, 3, 2, 3, z2bf);

    // ---- Layer 2
    k_gather<1><<<GG, 256, 0, stream>>>(z2bf, rowptr, eidx, st[3], st[3] + 256, Gam[3], Bet[3],
                                        (ushort4*)aggbf);
    gemm1(aggbf, 4, 4);                     // z1 bf16 in aggbf
    // final: bf16 z1 + BN staged -> f32 OUT (no stats)
    k_gemm<true, true, false, false><<<1563, 256, 0, stream>>>(
        aggbf, Wf + (size_t)5 * 65536, Bias[5], st[4], st[4] + 256, Gam[4], Bet[4],
        OUT, nullptr, nullptr, NN);
}